// Round 1
// baseline (2275.601 us; speedup 1.0000x reference)
//
#include <hip/hip_runtime.h>

#define KCODES 512
#define DIM 64
#define NB 32
#define NH 64
#define NW 64
#define NPTS (NB*NH*NW)     // 131072
#define HW (NH*NW)          // 4096

// ---- output layout (floats) ----
#define O_OUT  0
#define O_LOSS 8388608
#define O_IDX  8388609
#define O_EMB  8519681
#define O_M    8552449
#define O_MM   8585217

// ---- workspace layout (floats) ----
#define W_DM   0                    // K*D segment sums
#define W_CNT  (KCODES*DIM)         // 32768: K counts
#define W_LOSS (W_CNT + KCODES)     // 33280: loss accumulator
#define W_C    (W_LOSS + 1)         // 33281: K codeword sq-norms
#define W_NEWM (W_C + KCODES)       // 33793: K smoothed new_M
#define W_TOTAL (W_NEWM + KCODES)   // 34305 floats ~ 137 KB

__global__ void cnorm_kernel(const float* __restrict__ emb, float* __restrict__ ws) {
    int k = blockIdx.x * blockDim.x + threadIdx.x;
    if (k >= KCODES) return;
    float s = 0.f;
    #pragma unroll
    for (int d = 0; d < DIM; ++d) { float v = emb[k*DIM + d]; s += v*v; }
    ws[W_C + k] = s;
}

__global__ __launch_bounds__(256) void assign_kernel(
    const float* __restrict__ enc, const float* __restrict__ emb,
    float* __restrict__ out, float* __restrict__ ws)
{
    __shared__ float Es[64*64];   // 64 codeword rows, 16 KB
    __shared__ float Cs[64];
    const int t = threadIdx.x;
    const int w = t & 63;                       // lane = W coordinate (coalesced)
    const int R = blockIdx.x * 4 + (t >> 6);    // (b,h) row index, 0..2047
    const int b = R >> 6, h = R & 63;

    // load this point's D=64 vector (each load instruction is a coalesced 256B)
    const float* px = enc + (size_t)b * DIM * HW + h * NW + w;
    float x[DIM];
    #pragma unroll
    for (int d = 0; d < DIM; ++d) x[d] = px[(size_t)d * HW];

    float best = 3.402823466e38f;
    int bidx = 0;
    for (int kc = 0; kc < KCODES; kc += 64) {
        __syncthreads();
        // stage 64x64 chunk of embeddings: 1024 float4, 4 per thread, coalesced
        const float4* esrc = (const float4*)(emb + kc * DIM);
        float4* edst = (float4*)Es;
        #pragma unroll
        for (int q = 0; q < 4; ++q) edst[t + q*256] = esrc[t + q*256];
        if (t < 64) Cs[t] = ws[W_C + kc + t];
        __syncthreads();

        for (int kk = 0; kk < 64; ++kk) {
            const float4* er = (const float4*)(Es + kk*64);   // broadcast reads
            float a0 = 0.f, a1 = 0.f, a2 = 0.f, a3 = 0.f;     // 4 indep FMA chains
            #pragma unroll
            for (int q = 0; q < 16; ++q) {
                float4 e = er[q];
                a0 += x[4*q+0]*e.x; a1 += x[4*q+1]*e.y;
                a2 += x[4*q+2]*e.z; a3 += x[4*q+3]*e.w;
            }
            float score = Cs[kk] - 2.f*((a0+a1)+(a2+a3));
            if (score < best) { best = score; bidx = kc + kk; }  // strict < = first-min
        }
    }

    // epilogue: quantized output (STE value == embeddings[idx]), loss, scatter
    const float* eq = emb + (size_t)bidx * DIM;
    float* po = out + O_OUT + (size_t)b * DIM * HW + h * NW + w;
    float* dm = ws + W_DM;
    float lsum = 0.f;
    #pragma unroll
    for (int d = 0; d < DIM; ++d) {
        float q = eq[d];                 // gather from L1/L2-resident 128KB table
        po[(size_t)d * HW] = q;          // coalesced store
        float df = q - x[d];
        lsum += df * df;
        atomicAdd(&dm[bidx*DIM + d], x[d]);
    }
    atomicAdd(&ws[W_CNT + bidx], 1.0f);
    out[O_IDX + (size_t)R*64 + w] = (float)bidx;

    // wave-reduce the loss partial (wave = 64 lanes)
    #pragma unroll
    for (int off = 32; off >= 1; off >>= 1) lsum += __shfl_down(lsum, off, 64);
    if (w == 0) atomicAdd(&ws[W_LOSS], lsum);
}

__global__ void finalizeA(const float* __restrict__ emaM,
                          float* __restrict__ out, float* __restrict__ ws)
{
    __shared__ float red[512];
    int k = threadIdx.x;  // 512 threads, one per codeword
    float nM = 0.99f * emaM[k] + 0.01f * ws[W_CNT + k];
    red[k] = nM;
    __syncthreads();
    for (int s = 256; s >= 1; s >>= 1) {
        if (k < s) red[k] += red[k + s];
        __syncthreads();
    }
    float Ntot = red[0];
    float sm = (nM + 1e-5f) / (Ntot + 1e-5f * (float)KCODES) * Ntot;
    ws[W_NEWM + k] = sm;
    out[O_MM + k] = sm;
    if (k == 0) out[O_LOSS] = 0.25f * ws[W_LOSS] / (float)((size_t)NPTS * DIM);
}

__global__ void finalizeB(const float* __restrict__ emam,
                          float* __restrict__ out, const float* __restrict__ ws)
{
    int i = blockIdx.x * blockDim.x + threadIdx.x;  // 0..32767
    int k = i >> 6;
    float nm = 0.99f * emam[i] + 0.01f * ws[W_DM + i];
    out[O_M + i] = nm;
    out[O_EMB + i] = nm / ws[W_NEWM + k];
}

extern "C" void kernel_launch(void* const* d_in, const int* in_sizes, int n_in,
                              void* d_out, int out_size, void* d_ws, size_t ws_size,
                              hipStream_t stream)
{
    const float* enc  = (const float*)d_in[0];
    const float* emb  = (const float*)d_in[1];
    const float* emam = (const float*)d_in[2];
    const float* emaM = (const float*)d_in[3];
    float* out = (float*)d_out;
    float* ws  = (float*)d_ws;

    hipMemsetAsync(ws, 0, (size_t)W_TOTAL * sizeof(float), stream);
    cnorm_kernel<<<2, 256, 0, stream>>>(emb, ws);
    assign_kernel<<<NPTS/256 / 1, 256, 0, stream>>>(enc, emb, out, ws); // 512 blocks
    finalizeA<<<1, 512, 0, stream>>>(emaM, out, ws);
    finalizeB<<<(KCODES*DIM)/256, 256, 0, stream>>>(emam, out, ws);
}

// Round 2
// 439.392 us; speedup vs baseline: 5.1790x; 5.1790x over previous
//
#include <hip/hip_runtime.h>

#define KCODES 512
#define DIM 64
#define NB 32
#define NH 64
#define NW 64
#define NPTS (NB*NH*NW)     // 131072
#define HW (NH*NW)          // 4096

// ---- output layout (floats) ----
#define O_OUT  0
#define O_LOSS 8388608
#define O_IDX  8388609
#define O_EMB  8519681
#define O_M    8552449
#define O_MM   8585217

// ---- workspace layout (floats) ----
#define W_DM   0                    // K*D segment sums
#define W_CNT  (KCODES*DIM)         // 32768: K counts
#define W_LOSS (W_CNT + KCODES)     // 33280: loss accumulator
#define W_C    (W_LOSS + 1)         // 33281: K codeword sq-norms
#define W_NEWM (W_C + KCODES)       // 33793: K smoothed new_M
#define W_TOTAL (W_NEWM + KCODES)   // 34305 floats ~ 137 KB

__global__ void cnorm_kernel(const float* __restrict__ emb, float* __restrict__ ws) {
    int k = blockIdx.x * blockDim.x + threadIdx.x;
    if (k >= KCODES) return;
    float s = 0.f;
    #pragma unroll
    for (int d = 0; d < DIM; ++d) { float v = emb[k*DIM + d]; s += v*v; }
    ws[W_C + k] = s;
}

// launch_bounds(256,2): VGPR cap 256 so x[64] stays in registers (round-1
// compiled to 64 VGPRs -> x[] was spilled to scratch -> VALUBusy 6.8%).
__global__ __launch_bounds__(256, 2) void assign_kernel(
    const float* __restrict__ enc, const float* __restrict__ emb,
    float* __restrict__ out, float* __restrict__ ws)
{
    __shared__ float Es[64*64];       // 64 codeword rows, 16 KB
    __shared__ float Cs[64];
    __shared__ float T[4][64][17];    // per-wave transpose tile, 17-stride pad
    const int t = threadIdx.x;
    const int w = t & 63;                       // lane = W coordinate (coalesced)
    const int wv = t >> 6;                      // wave id 0..3
    const int R = blockIdx.x * 4 + wv;          // (b,h) row index, 0..2047
    const int b = R >> 6, h = R & 63;

    // load this point's D=64 vector (each load instruction is a coalesced 256B)
    const float* px = enc + (size_t)b * DIM * HW + h * NW + w;
    float x[DIM];
    #pragma unroll
    for (int d = 0; d < DIM; ++d) x[d] = px[(size_t)d * HW];

    // ---- distance phase: bit-identical to round 1 (argmin must not move) ----
    float best = 3.402823466e38f;
    int bidx = 0;
    for (int kc = 0; kc < KCODES; kc += 64) {
        __syncthreads();
        const float4* esrc = (const float4*)(emb + kc * DIM);
        float4* edst = (float4*)Es;
        #pragma unroll
        for (int q = 0; q < 4; ++q) edst[t + q*256] = esrc[t + q*256];
        if (t < 64) Cs[t] = ws[W_C + kc + t];
        __syncthreads();

        for (int kk = 0; kk < 64; ++kk) {
            const float4* er = (const float4*)(Es + kk*64);   // broadcast reads
            float a0 = 0.f, a1 = 0.f, a2 = 0.f, a3 = 0.f;     // 4 indep FMA chains
            #pragma unroll
            for (int q = 0; q < 16; ++q) {
                float4 e = er[q];
                a0 += x[4*q+0]*e.x; a1 += x[4*q+1]*e.y;
                a2 += x[4*q+2]*e.z; a3 += x[4*q+3]*e.w;
            }
            float score = Cs[kk] - 2.f*((a0+a1)+(a2+a3));
            if (score < best) { best = score; bidx = kc + kk; }  // strict < = first-min
        }
    }
    __syncthreads();   // dist phase done in all waves before T-tile use

    // ---- epilogue: wave-transposed scatter/gather ----
    // For each 16-dim chunk c: lanes split as (point-subgroup pg 0..3, dim dl 0..15)
    // so atomics / emb reads are 4 x 64B contiguous runs per instruction instead
    // of 64 scattered 4B ops.
    float* po = out + O_OUT + (size_t)b * DIM * HW + h * NW + w;
    float* dm = ws + W_DM;
    const int pg = w >> 4;      // which of 4 points this lane serves
    const int dl = w & 15;      // dim-in-chunk
    float lsum = 0.f;

    for (int c = 0; c < 4; ++c) {
        // A: deposit own x chunk (row w)
        #pragma unroll
        for (int i = 0; i < 16; ++i) T[wv][w][i] = x[c*16 + i];
        __syncthreads();
        // B: transposed workers — 4 points x 16 dims per instruction
        #pragma unroll
        for (int jj = 0; jj < 16; ++jj) {
            int p = jj*4 + pg;
            int kb = __shfl(bidx, p, 64);
            float xv = T[wv][p][dl];
            int addr = kb*64 + c*16 + dl;
            atomicAdd(&dm[addr], xv);
            T[wv][p][dl] = emb[addr];   // same lane/addr overwrite: safe
        }
        __syncthreads();
        // C: un-transpose — coalesced quantized store + loss (reads own row)
        #pragma unroll
        for (int i = 0; i < 16; ++i) {
            float q = T[wv][w][i];
            po[(size_t)(c*16 + i) * HW] = q;
            float df = q - x[c*16 + i];
            lsum = fmaf(df, df, lsum);
        }
        // no barrier needed: next A writes own row (same-lane), next B is
        // after the A->B barrier which orders this C's reads.
    }

    atomicAdd(&ws[W_CNT + bidx], 1.0f);
    out[O_IDX + (size_t)R*64 + w] = (float)bidx;

    // wave-reduce the loss partial (wave = 64 lanes)
    #pragma unroll
    for (int off = 32; off >= 1; off >>= 1) lsum += __shfl_down(lsum, off, 64);
    if (w == 0) atomicAdd(&ws[W_LOSS], lsum);
}

__global__ void finalizeA(const float* __restrict__ emaM,
                          float* __restrict__ out, float* __restrict__ ws)
{
    __shared__ float red[512];
    int k = threadIdx.x;  // 512 threads, one per codeword
    float nM = 0.99f * emaM[k] + 0.01f * ws[W_CNT + k];
    red[k] = nM;
    __syncthreads();
    for (int s = 256; s >= 1; s >>= 1) {
        if (k < s) red[k] += red[k + s];
        __syncthreads();
    }
    float Ntot = red[0];
    float sm = (nM + 1e-5f) / (Ntot + 1e-5f * (float)KCODES) * Ntot;
    ws[W_NEWM + k] = sm;
    out[O_MM + k] = sm;
    if (k == 0) out[O_LOSS] = 0.25f * ws[W_LOSS] / (float)((size_t)NPTS * DIM);
}

__global__ void finalizeB(const float* __restrict__ emam,
                          float* __restrict__ out, const float* __restrict__ ws)
{
    int i = blockIdx.x * blockDim.x + threadIdx.x;  // 0..32767
    int k = i >> 6;
    float nm = 0.99f * emam[i] + 0.01f * ws[W_DM + i];
    out[O_M + i] = nm;
    out[O_EMB + i] = nm / ws[W_NEWM + k];
}

extern "C" void kernel_launch(void* const* d_in, const int* in_sizes, int n_in,
                              void* d_out, int out_size, void* d_ws, size_t ws_size,
                              hipStream_t stream)
{
    const float* enc  = (const float*)d_in[0];
    const float* emb  = (const float*)d_in[1];
    const float* emam = (const float*)d_in[2];
    const float* emaM = (const float*)d_in[3];
    float* out = (float*)d_out;
    float* ws  = (float*)d_ws;

    hipMemsetAsync(ws, 0, (size_t)W_TOTAL * sizeof(float), stream);
    cnorm_kernel<<<2, 256, 0, stream>>>(emb, ws);
    assign_kernel<<<NPTS/256, 256, 0, stream>>>(enc, emb, out, ws); // 512 blocks
    finalizeA<<<1, 512, 0, stream>>>(emaM, out, ws);
    finalizeB<<<(KCODES*DIM)/256, 256, 0, stream>>>(emam, out, ws);
}